// Round 8
// baseline (202.591 us; speedup 1.0000x reference)
//
#include <hip/hip_runtime.h>
#include <math.h>

#define NBINS 64
#define HIST_ELEMS (NBINS*NBINS)
#define PTS_PER_BLOCK 2304      // 384 blocks/n * 2304 = 884736 = P; grid 768 = 3/CU even
#define GXN 384                 // blocks per sample
#define CHUNKS 18               // per wave: 2304 / (4 waves * 32)
// weight = exp2(-(u*SQK - b*SQK)^2); SQK = sqrt(8192/63^2*log2(e))
#define SQK 1.7256062f

typedef float f4 __attribute__((ext_vector_type(4)));
typedef float f32x4 __attribute__((ext_vector_type(4)));
typedef _Float16 half8 __attribute__((ext_vector_type(8)));
typedef int int4v __attribute__((ext_vector_type(4)));

// ---- monotone float<->uint keys ----
static __device__ __forceinline__ unsigned f2key(float f) {
    unsigned u = __float_as_uint(f);
    return (u & 0x80000000u) ? ~u : (u | 0x80000000u);
}
static __device__ __forceinline__ float key2f(unsigned u) {
    return (u & 0x80000000u) ? __uint_as_float(u & 0x7fffffffu) : __uint_as_float(~u);
}

static __device__ __forceinline__ half8 pack8(const float* w) {
    int4v v;
    v[0] = __builtin_bit_cast(int, __builtin_amdgcn_cvt_pkrtz(w[0], w[1]));
    v[1] = __builtin_bit_cast(int, __builtin_amdgcn_cvt_pkrtz(w[2], w[3]));
    v[2] = __builtin_bit_cast(int, __builtin_amdgcn_cvt_pkrtz(w[4], w[5]));
    v[3] = __builtin_bit_cast(int, __builtin_amdgcn_cvt_pkrtz(w[6], w[7]));
    return __builtin_bit_cast(half8, v);
}

// ws layout: uint mm[8]: [0..3]=min keys, [4..7]=min of ~key (i.e. max) — ALL init 0xFF
//            @256: float hist[2][4096] | @33024: float bh[2*GXN][4096]
__global__ __launch_bounds__(256) void minmax_kernel(const float* __restrict__ tar,
                                                     const float* __restrict__ src,
                                                     unsigned* __restrict__ mm, int P) {
    const int n = blockIdx.y;
    const int t = blockIdx.z;
    const f4* x = (const f4*)((t == 0 ? tar : src) + (size_t)n * P);
    const int n4 = P / 4;
    float lmin = INFINITY, lmax = -INFINITY;
    for (int i = blockIdx.x * blockDim.x + threadIdx.x; i < n4; i += gridDim.x * blockDim.x) {
        f4 v = x[i];
        lmin = fminf(lmin, fminf(fminf(v[0], v[1]), fminf(v[2], v[3])));
        lmax = fmaxf(lmax, fmaxf(fmaxf(v[0], v[1]), fmaxf(v[2], v[3])));
    }
    for (int off = 32; off > 0; off >>= 1) {
        lmin = fminf(lmin, __shfl_down(lmin, off, 64));
        lmax = fmaxf(lmax, __shfl_down(lmax, off, 64));
    }
    __shared__ float smin[4], smax[4];
    const int lane = threadIdx.x & 63, wave = threadIdx.x >> 6;
    if (lane == 0) { smin[wave] = lmin; smax[wave] = lmax; }
    __syncthreads();
    if (threadIdx.x == 0) {
        float m = fminf(fminf(smin[0], smin[1]), fminf(smin[2], smin[3]));
        float M = fmaxf(fmaxf(smax[0], smax[1]), fmaxf(smax[2], smax[3]));
        atomicMin(&mm[n * 2 + t], f2key(m));
        atomicMin(&mm[4 + n * 2 + t], ~f2key(M));   // max via min of complement
    }
}

// Joint histogram as 64x64xP GEMM via MFMA f16.  One staging phase per block
// (2304 pts, 18 KB), 18 K=32 chunks per wave barrier-free, grid 768 = 3/CU.
// A[m][k]: m=lane&15 (+16*mt), k=quad*8+j ; B[k][n]: n=lane&15, k=quad*8+j
// C/D: col=lane&15, row=quad*4+reg.
template <int STAGED>
__global__ __launch_bounds__(256) void mfma_hist_kernel(const float* __restrict__ tar,
                                                        const float* __restrict__ src,
                                                        const unsigned* __restrict__ mm,
                                                        float* __restrict__ bh,
                                                        float* __restrict__ hist,
                                                        int P) {
    const int n = blockIdx.y;
    const int bx = blockIdx.x;
    const int tid = threadIdx.x;
    const int lane = tid & 63, wave = tid >> 6;
    const int mlane = lane & 15, quad = lane >> 4;

    __shared__ float su_t[PTS_PER_BLOCK], su_s[PTS_PER_BLOCK];
    __shared__ float lh[HIST_ELEMS];
    {
        f4 z = {0.f, 0.f, 0.f, 0.f};
        f4* l4 = (f4*)lh;
        for (int i = tid; i < HIST_ELEMS / 4; i += 256) l4[i] = z;
    }

    const float tmin = key2f(mm[n * 2 + 0]);
    const float tmax = key2f(~mm[4 + n * 2 + 0]);
    const float smin = key2f(mm[n * 2 + 1]);
    const float smax = key2f(~mm[4 + n * 2 + 1]);
    const float tk = 63.0f / (tmax - tmin + 1e-10f) * SQK;
    const float sk = 63.0f / (smax - smin + 1e-10f) * SQK;
    const float toff = tmin * tk, soff = smin * sk;

    // --- single staging phase: 576 f4 per tensor, coalesced ---
    {
        const f4* tg = (const f4*)(tar + (size_t)n * P + (size_t)bx * PTS_PER_BLOCK);
        const f4* sg = (const f4*)(src + (size_t)n * P + (size_t)bx * PTS_PER_BLOCK);
        f4* st4 = (f4*)su_t;
        f4* ss4 = (f4*)su_s;
        #pragma unroll
        for (int k = 0; k < 2; ++k) {
            const int i = tid + k * 256;
            f4 tv = tg[i], sv = sg[i];
            f4 utv, usv;
            #pragma unroll
            for (int c = 0; c < 4; ++c) {
                utv[c] = fmaf(tv[c], tk, -toff);
                usv[c] = fmaf(sv[c], sk, -soff);
            }
            st4[i] = utv;
            ss4[i] = usv;
        }
        if (tid < 64) {
            const int i = 512 + tid;
            f4 tv = tg[i], sv = sg[i];
            f4 utv, usv;
            #pragma unroll
            for (int c = 0; c < 4; ++c) {
                utv[c] = fmaf(tv[c], tk, -toff);
                usv[c] = fmaf(sv[c], sk, -soff);
            }
            st4[i] = utv;
            ss4[i] = usv;
        }
    }
    __syncthreads();   // staging + lh zeroing complete

    float mhat[4];
    #pragma unroll
    for (int mt = 0; mt < 4; ++mt) mhat[mt] = (float)(mlane + 16 * mt) * SQK;

    f32x4 acc[4][4];
    #pragma unroll
    for (int a = 0; a < 4; ++a)
        #pragma unroll
        for (int b = 0; b < 4; ++b) acc[a][b] = (f32x4){0.f, 0.f, 0.f, 0.f};

    // --- compute: wave owns 576 points = 18 chunks of K=32, barrier-free ---
    const int kwbase = wave * (32 * CHUNKS) + quad * 8;
    #pragma unroll 3
    for (int c = 0; c < CHUNKS; ++c) {
        const int kbase = kwbase + c * 32;
        const f4* pt4 = (const f4*)&su_t[kbase];
        const f4* ps4 = (const f4*)&su_s[kbase];
        f4 ta = pt4[0], tb = pt4[1];
        f4 sa = ps4[0], sb = ps4[1];
        float ut[8] = {ta[0], ta[1], ta[2], ta[3], tb[0], tb[1], tb[2], tb[3]};
        float us[8] = {sa[0], sa[1], sa[2], sa[3], sb[0], sb[1], sb[2], sb[3]};

        half8 af[4], bf[4];
        #pragma unroll
        for (int mt = 0; mt < 4; ++mt) {
            float w[8];
            #pragma unroll
            for (int j = 0; j < 8; ++j) {
                float d = ut[j] - mhat[mt];
                w[j] = __builtin_amdgcn_exp2f(-(d * d));
            }
            af[mt] = pack8(w);
        }
        #pragma unroll
        for (int nt = 0; nt < 4; ++nt) {
            float w[8];
            #pragma unroll
            for (int j = 0; j < 8; ++j) {
                float d = us[j] - mhat[nt];
                w[j] = __builtin_amdgcn_exp2f(-(d * d));
            }
            bf[nt] = pack8(w);
        }
        #pragma unroll
        for (int mt = 0; mt < 4; ++mt)
            #pragma unroll
            for (int nt = 0; nt < 4; ++nt)
                acc[mt][nt] = __builtin_amdgcn_mfma_f32_16x16x32_f16(
                    af[mt], bf[nt], acc[mt][nt], 0, 0, 0);
    }

    // --- combine 4 waves' 64x64 accumulators in LDS ---
    #pragma unroll
    for (int mt = 0; mt < 4; ++mt)
        #pragma unroll
        for (int nt = 0; nt < 4; ++nt)
            #pragma unroll
            for (int r = 0; r < 4; ++r) {
                int row = 16 * mt + 4 * quad + r;
                int col = 16 * nt + mlane;
                unsafeAtomicAdd(&lh[row * NBINS + col], acc[mt][nt][r]);
            }
    __syncthreads();

    if (STAGED) {
        f4* dst = (f4*)(bh + ((size_t)n * GXN + bx) * HIST_ELEMS);
        const f4* l4 = (const f4*)lh;
        for (int i = tid; i < HIST_ELEMS / 4; i += 256) dst[i] = l4[i];
    } else {
        float* gh = hist + (size_t)n * HIST_ELEMS;
        for (int i = tid; i < HIST_ELEMS; i += 256) unsafeAtomicAdd(&gh[i], lh[i]);
    }
}

__global__ __launch_bounds__(256) void reduce_kernel(const float* __restrict__ bh,
                                                     float* __restrict__ hist) {
    const int g = blockIdx.x * 256 + threadIdx.x;   // 0..8191
    const int n = g >> 12, e = g & 4095;
    const float* p = bh + ((size_t)n * GXN) * HIST_ELEMS + e;
    float sum = 0.0f;
    #pragma unroll 8
    for (int b = 0; b < GXN; ++b) sum += p[(size_t)b * HIST_ELEMS];
    hist[g] = sum;
}

static __device__ __forceinline__ float block_reduce_sum(float v, float* buf) {
    for (int off = 32; off > 0; off >>= 1) v += __shfl_down(v, off, 64);
    const int lane = threadIdx.x & 63, wave = threadIdx.x >> 6;
    __syncthreads();
    if (lane == 0) buf[wave] = v;
    __syncthreads();
    return buf[0] + buf[1] + buf[2] + buf[3];
}

__global__ __launch_bounds__(256) void finalize_kernel(const float* __restrict__ ghist,
                                                       float* __restrict__ out) {
    __shared__ float buf[4];
    __shared__ float colp[4][NBINS];
    __shared__ float rowsum[NBINS], colsum[NBINS];
    const int tid = threadIdx.x;
    float acc = 0.0f;
    for (int n = 0; n < 2; ++n) {
        const float* h = ghist + n * HIST_ELEMS;
        {
            int r = tid >> 2, q = tid & 3;
            const float* hp = h + r * NBINS + q * 16;
            float sv = 0.0f;
            #pragma unroll
            for (int k = 0; k < 16; ++k) sv += hp[k];
            sv += __shfl_down(sv, 1, 64);
            sv += __shfl_down(sv, 2, 64);
            if (q == 0) rowsum[r] = sv;
        }
        {
            int c = tid & 63, g = tid >> 6;
            const float* hp = h + (g * 16) * NBINS + c;
            float sv = 0.0f;
            #pragma unroll
            for (int k = 0; k < 16; ++k) sv += hp[k * NBINS];
            colp[g][c] = sv;
        }
        __syncthreads();
        if (tid < NBINS)
            colsum[tid] = colp[0][tid] + colp[1][tid] + colp[2][tid] + colp[3][tid];
        __syncthreads();

        float tv = (tid < NBINS) ? rowsum[tid] : 0.0f;
        float total = block_reduce_sum(tv, buf);
        float inv = 1.0f / total;

        float ej = 0.0f;
        for (int i = tid; i < HIST_ELEMS; i += 256) {
            float p = h[i] * inv;
            ej += p * __logf(p + 1e-10f);
        }
        float entj = -block_reduce_sum(ej, buf);

        float em = 0.0f;
        if (tid < NBINS) {
            float p = rowsum[tid] * inv;
            em = p * __logf(p + 1e-10f);
        } else if (tid < 2 * NBINS) {
            float p = colsum[tid - NBINS] * inv;
            em = p * __logf(p + 1e-10f);
        }
        float ents = -block_reduce_sum(em, buf);

        acc += ents / entj;
        __syncthreads();
    }
    if (tid == 0) out[0] = -0.5f * acc;
}

extern "C" void kernel_launch(void* const* d_in, const int* in_sizes, int n_in,
                              void* d_out, int out_size, void* d_ws, size_t ws_size,
                              hipStream_t stream) {
    const float* tar = (const float*)d_in[0];
    const float* src = (const float*)d_in[1];
    const int N = 2;
    const int P = in_sizes[0] / N;  // 884736

    unsigned* mm = (unsigned*)d_ws;
    float* hist = (float*)((char*)d_ws + 256);
    float* bh = (float*)((char*)d_ws + 256 + 2 * HIST_ELEMS * sizeof(float));
    float* out = (float*)d_out;

    const size_t need = 256 + (size_t)2 * HIST_ELEMS * 4 + (size_t)2 * GXN * HIST_ELEMS * 4;

    // single memset: all 8 mm slots -> 0xFFFFFFFF (max stored as min of ~key)
    hipMemsetAsync(d_ws, 0xFF, 32, stream);
    minmax_kernel<<<dim3(128, N, 2), 256, 0, stream>>>(tar, src, mm, P);
    if (ws_size >= need) {
        mfma_hist_kernel<1><<<dim3(GXN, N), 256, 0, stream>>>(tar, src, mm, bh, hist, P);
        reduce_kernel<<<32, 256, 0, stream>>>(bh, hist);
    } else {
        hipMemsetAsync((char*)d_ws + 256, 0x00, 2 * HIST_ELEMS * sizeof(float), stream);
        mfma_hist_kernel<0><<<dim3(GXN, N), 256, 0, stream>>>(tar, src, mm, bh, hist, P);
    }
    finalize_kernel<<<1, 256, 0, stream>>>(hist, out);
}

// Round 9
// 138.020 us; speedup vs baseline: 1.4678x; 1.4678x over previous
//
#include <hip/hip_runtime.h>
#include <math.h>

#define NBINS 64
#define HIST_ELEMS (NBINS*NBINS)
#define PTS_PER_BLOCK 3456      // 256 blocks/n * 3456 = 884736 = P; grid 512 = 2/CU even
#define GXN 256                 // blocks per sample
#define CHUNKS 27               // per wave: 3456 / (4 waves * 32)
#define LSTRIDE 68              // col-major lh stride (68%32=4 -> b128 2-way banks = free)
// weight = exp2(-(u*SQK - b*SQK)^2); SQK = sqrt(8192/63^2*log2(e))
#define SQK 1.7256062f

typedef float f4 __attribute__((ext_vector_type(4)));
typedef float f32x4 __attribute__((ext_vector_type(4)));
typedef _Float16 half8 __attribute__((ext_vector_type(8)));
typedef int int4v __attribute__((ext_vector_type(4)));

// ---- monotone float<->uint keys ----
static __device__ __forceinline__ unsigned f2key(float f) {
    unsigned u = __float_as_uint(f);
    return (u & 0x80000000u) ? ~u : (u | 0x80000000u);
}
static __device__ __forceinline__ float key2f(unsigned u) {
    return (u & 0x80000000u) ? __uint_as_float(u & 0x7fffffffu) : __uint_as_float(~u);
}

static __device__ __forceinline__ half8 pack8(const float* w) {
    int4v v;
    v[0] = __builtin_bit_cast(int, __builtin_amdgcn_cvt_pkrtz(w[0], w[1]));
    v[1] = __builtin_bit_cast(int, __builtin_amdgcn_cvt_pkrtz(w[2], w[3]));
    v[2] = __builtin_bit_cast(int, __builtin_amdgcn_cvt_pkrtz(w[4], w[5]));
    v[3] = __builtin_bit_cast(int, __builtin_amdgcn_cvt_pkrtz(w[6], w[7]));
    return __builtin_bit_cast(half8, v);
}

// ws layout: uint mm[8]: [0..3]=min keys, [4..7]=min of ~key (i.e. max) — ALL init 0xFF
//            @256: float hist[2][4096] | @33024: float bh[2*GXN][4096]
// NOTE: hist/bh hold the TRANSPOSED joint histogram (src-bin-major). The MI
// loss is symmetric under transpose (marginals swap, their entropies are
// summed; joint entropy invariant), so downstream kernels need no change.
__global__ __launch_bounds__(256) void minmax_kernel(const float* __restrict__ tar,
                                                     const float* __restrict__ src,
                                                     unsigned* __restrict__ mm, int P) {
    const int n = blockIdx.y;
    const int t = blockIdx.z;
    const f4* x = (const f4*)((t == 0 ? tar : src) + (size_t)n * P);
    const int n4 = P / 4;
    float lmin = INFINITY, lmax = -INFINITY;
    for (int i = blockIdx.x * blockDim.x + threadIdx.x; i < n4; i += gridDim.x * blockDim.x) {
        f4 v = x[i];
        lmin = fminf(lmin, fminf(fminf(v[0], v[1]), fminf(v[2], v[3])));
        lmax = fmaxf(lmax, fmaxf(fmaxf(v[0], v[1]), fmaxf(v[2], v[3])));
    }
    for (int off = 32; off > 0; off >>= 1) {
        lmin = fminf(lmin, __shfl_down(lmin, off, 64));
        lmax = fmaxf(lmax, __shfl_down(lmax, off, 64));
    }
    __shared__ float smin[4], smax[4];
    const int lane = threadIdx.x & 63, wave = threadIdx.x >> 6;
    if (lane == 0) { smin[wave] = lmin; smax[wave] = lmax; }
    __syncthreads();
    if (threadIdx.x == 0) {
        float m = fminf(fminf(smin[0], smin[1]), fminf(smin[2], smin[3]));
        float M = fmaxf(fmaxf(smax[0], smax[1]), fmaxf(smax[2], smax[3]));
        atomicMin(&mm[n * 2 + t], f2key(m));
        atomicMin(&mm[4 + n * 2 + t], ~f2key(M));   // max via min of complement
    }
}

// Joint histogram as 64x64xP GEMM via MFMA f16.  R7 compute core (512 blocks
// = 2/CU, one staging phase, 27 barrier-free K=32 chunks/wave).  Epilogue:
// serial-wave NON-ATOMIC combine (the 20us/block LDS-atomic fixed cost was
// the R6-R8 bottleneck: 16384 lane-atomics @ 0.33/cyc/CU = 49k cyc = 20us).
// A[m][k]: m=lane&15 (+16*mt), k=quad*8+j ; B[k][n]: n=lane&15, k=quad*8+j
// C/D: col=lane&15, row=quad*4+reg -> lane's 4 acc values are 4 consecutive
// rows of one col => col-major lh makes them one ds_write_b128.
template <int STAGED>
__global__ __launch_bounds__(256) void mfma_hist_kernel(const float* __restrict__ tar,
                                                        const float* __restrict__ src,
                                                        const unsigned* __restrict__ mm,
                                                        float* __restrict__ bh,
                                                        float* __restrict__ hist,
                                                        int P) {
    const int n = blockIdx.y;
    const int bx = blockIdx.x;
    const int tid = threadIdx.x;
    const int lane = tid & 63, wave = tid >> 6;
    const int mlane = lane & 15, quad = lane >> 4;

    __shared__ float su_t[PTS_PER_BLOCK], su_s[PTS_PER_BLOCK];
    __shared__ float lh[NBINS * LSTRIDE];   // col-major: lh[col*LSTRIDE + row]

    const float tmin = key2f(mm[n * 2 + 0]);
    const float tmax = key2f(~mm[4 + n * 2 + 0]);
    const float smin = key2f(mm[n * 2 + 1]);
    const float smax = key2f(~mm[4 + n * 2 + 1]);
    const float tk = 63.0f / (tmax - tmin + 1e-10f) * SQK;
    const float sk = 63.0f / (smax - smin + 1e-10f) * SQK;
    const float toff = tmin * tk, soff = smin * sk;

    // --- single staging phase: 864 f4 per tensor, coalesced ---
    {
        const f4* tg = (const f4*)(tar + (size_t)n * P + (size_t)bx * PTS_PER_BLOCK);
        const f4* sg = (const f4*)(src + (size_t)n * P + (size_t)bx * PTS_PER_BLOCK);
        f4* st4 = (f4*)su_t;
        f4* ss4 = (f4*)su_s;
        #pragma unroll
        for (int k = 0; k < 3; ++k) {
            const int i = tid + k * 256;
            f4 tv = tg[i], sv = sg[i];
            f4 utv, usv;
            #pragma unroll
            for (int c = 0; c < 4; ++c) {
                utv[c] = fmaf(tv[c], tk, -toff);
                usv[c] = fmaf(sv[c], sk, -soff);
            }
            st4[i] = utv;
            ss4[i] = usv;
        }
        if (tid < 96) {
            const int i = 768 + tid;
            f4 tv = tg[i], sv = sg[i];
            f4 utv, usv;
            #pragma unroll
            for (int c = 0; c < 4; ++c) {
                utv[c] = fmaf(tv[c], tk, -toff);
                usv[c] = fmaf(sv[c], sk, -soff);
            }
            st4[i] = utv;
            ss4[i] = usv;
        }
    }
    __syncthreads();   // staging complete

    float mhat[4];
    #pragma unroll
    for (int mt = 0; mt < 4; ++mt) mhat[mt] = (float)(mlane + 16 * mt) * SQK;

    f32x4 acc[4][4];
    #pragma unroll
    for (int a = 0; a < 4; ++a)
        #pragma unroll
        for (int b = 0; b < 4; ++b) acc[a][b] = (f32x4){0.f, 0.f, 0.f, 0.f};

    // --- compute: wave owns 864 points = 27 chunks of K=32, barrier-free ---
    const int kwbase = wave * (32 * CHUNKS) + quad * 8;
    #pragma unroll 3
    for (int c = 0; c < CHUNKS; ++c) {
        const int kbase = kwbase + c * 32;
        const f4* pt4 = (const f4*)&su_t[kbase];
        const f4* ps4 = (const f4*)&su_s[kbase];
        f4 ta = pt4[0], tb = pt4[1];
        f4 sa = ps4[0], sb = ps4[1];
        float ut[8] = {ta[0], ta[1], ta[2], ta[3], tb[0], tb[1], tb[2], tb[3]};
        float us[8] = {sa[0], sa[1], sa[2], sa[3], sb[0], sb[1], sb[2], sb[3]};

        half8 af[4], bf[4];
        #pragma unroll
        for (int mt = 0; mt < 4; ++mt) {
            float w[8];
            #pragma unroll
            for (int j = 0; j < 8; ++j) {
                float d = ut[j] - mhat[mt];
                w[j] = __builtin_amdgcn_exp2f(-(d * d));
            }
            af[mt] = pack8(w);
        }
        #pragma unroll
        for (int nt = 0; nt < 4; ++nt) {
            float w[8];
            #pragma unroll
            for (int j = 0; j < 8; ++j) {
                float d = us[j] - mhat[nt];
                w[j] = __builtin_amdgcn_exp2f(-(d * d));
            }
            bf[nt] = pack8(w);
        }
        #pragma unroll
        for (int mt = 0; mt < 4; ++mt)
            #pragma unroll
            for (int nt = 0; nt < 4; ++nt)
                acc[mt][nt] = __builtin_amdgcn_mfma_f32_16x16x32_f16(
                    af[mt], bf[nt], acc[mt][nt], 0, 0, 0);
    }

    // --- serial-wave NON-ATOMIC combine into col-major lh ---
    // lane's tile element: col = 16*nt + mlane, rows 16*mt + 4*quad + (0..3)
    // -> one f4 (ds_write_b128) at lh[col*LSTRIDE + 16*mt + 4*quad]
    #pragma unroll
    for (int w = 0; w < 4; ++w) {
        if (wave == w) {
            #pragma unroll
            for (int nt = 0; nt < 4; ++nt)
                #pragma unroll
                for (int mt = 0; mt < 4; ++mt) {
                    f4* p = (f4*)&lh[(16 * nt + mlane) * LSTRIDE + 16 * mt + 4 * quad];
                    if (w == 0) {
                        *p = acc[mt][nt];
                    } else {
                        f4 v = *p;
                        v += acc[mt][nt];
                        *p = v;
                    }
                }
        }
        __syncthreads();
    }

    if (STAGED) {
        // compact col-major lh -> dense 4096-float tile (transposed hist)
        f4* dst = (f4*)(bh + ((size_t)n * GXN + bx) * HIST_ELEMS);
        #pragma unroll
        for (int k = 0; k < 4; ++k) {
            const int i4 = tid + k * 256;          // 0..1023
            const int c = i4 >> 4, r4 = (i4 & 15) * 4;
            dst[i4] = *(const f4*)&lh[c * LSTRIDE + r4];
        }
    } else {
        float* gh = hist + (size_t)n * HIST_ELEMS;
        for (int i = tid; i < HIST_ELEMS; i += 256) {
            const int c = i >> 6, r = i & 63;
            unsafeAtomicAdd(&gh[i], lh[c * LSTRIDE + r]);
        }
    }
}

__global__ __launch_bounds__(256) void reduce_kernel(const float* __restrict__ bh,
                                                     float* __restrict__ hist) {
    const int g = blockIdx.x * 256 + threadIdx.x;   // 0..8191
    const int n = g >> 12, e = g & 4095;
    const float* p = bh + ((size_t)n * GXN) * HIST_ELEMS + e;
    float sum = 0.0f;
    #pragma unroll 8
    for (int b = 0; b < GXN; ++b) sum += p[(size_t)b * HIST_ELEMS];
    hist[g] = sum;
}

static __device__ __forceinline__ float block_reduce_sum(float v, float* buf) {
    for (int off = 32; off > 0; off >>= 1) v += __shfl_down(v, off, 64);
    const int lane = threadIdx.x & 63, wave = threadIdx.x >> 6;
    __syncthreads();
    if (lane == 0) buf[wave] = v;
    __syncthreads();
    return buf[0] + buf[1] + buf[2] + buf[3];
}

__global__ __launch_bounds__(256) void finalize_kernel(const float* __restrict__ ghist,
                                                       float* __restrict__ out) {
    __shared__ float buf[4];
    __shared__ float colp[4][NBINS];
    __shared__ float rowsum[NBINS], colsum[NBINS];
    const int tid = threadIdx.x;
    float acc = 0.0f;
    for (int n = 0; n < 2; ++n) {
        const float* h = ghist + n * HIST_ELEMS;
        {
            int r = tid >> 2, q = tid & 3;
            const float* hp = h + r * NBINS + q * 16;
            float sv = 0.0f;
            #pragma unroll
            for (int k = 0; k < 16; ++k) sv += hp[k];
            sv += __shfl_down(sv, 1, 64);
            sv += __shfl_down(sv, 2, 64);
            if (q == 0) rowsum[r] = sv;
        }
        {
            int c = tid & 63, g = tid >> 6;
            const float* hp = h + (g * 16) * NBINS + c;
            float sv = 0.0f;
            #pragma unroll
            for (int k = 0; k < 16; ++k) sv += hp[k * NBINS];
            colp[g][c] = sv;
        }
        __syncthreads();
        if (tid < NBINS)
            colsum[tid] = colp[0][tid] + colp[1][tid] + colp[2][tid] + colp[3][tid];
        __syncthreads();

        float tv = (tid < NBINS) ? rowsum[tid] : 0.0f;
        float total = block_reduce_sum(tv, buf);
        float inv = 1.0f / total;

        float ej = 0.0f;
        for (int i = tid; i < HIST_ELEMS; i += 256) {
            float p = h[i] * inv;
            ej += p * __logf(p + 1e-10f);
        }
        float entj = -block_reduce_sum(ej, buf);

        float em = 0.0f;
        if (tid < NBINS) {
            float p = rowsum[tid] * inv;
            em = p * __logf(p + 1e-10f);
        } else if (tid < 2 * NBINS) {
            float p = colsum[tid - NBINS] * inv;
            em = p * __logf(p + 1e-10f);
        }
        float ents = -block_reduce_sum(em, buf);

        acc += ents / entj;
        __syncthreads();
    }
    if (tid == 0) out[0] = -0.5f * acc;
}

extern "C" void kernel_launch(void* const* d_in, const int* in_sizes, int n_in,
                              void* d_out, int out_size, void* d_ws, size_t ws_size,
                              hipStream_t stream) {
    const float* tar = (const float*)d_in[0];
    const float* src = (const float*)d_in[1];
    const int N = 2;
    const int P = in_sizes[0] / N;  // 884736

    unsigned* mm = (unsigned*)d_ws;
    float* hist = (float*)((char*)d_ws + 256);
    float* bh = (float*)((char*)d_ws + 256 + 2 * HIST_ELEMS * sizeof(float));
    float* out = (float*)d_out;

    const size_t need = 256 + (size_t)2 * HIST_ELEMS * 4 + (size_t)2 * GXN * HIST_ELEMS * 4;

    // single memset: all 8 mm slots -> 0xFFFFFFFF (max stored as min of ~key)
    hipMemsetAsync(d_ws, 0xFF, 32, stream);
    minmax_kernel<<<dim3(128, N, 2), 256, 0, stream>>>(tar, src, mm, P);
    if (ws_size >= need) {
        mfma_hist_kernel<1><<<dim3(GXN, N), 256, 0, stream>>>(tar, src, mm, bh, hist, P);
        reduce_kernel<<<32, 256, 0, stream>>>(bh, hist);
    } else {
        hipMemsetAsync((char*)d_ws + 256, 0x00, 2 * HIST_ELEMS * sizeof(float), stream);
        mfma_hist_kernel<0><<<dim3(GXN, N), 256, 0, stream>>>(tar, src, mm, bh, hist, P);
    }
    finalize_kernel<<<1, 256, 0, stream>>>(hist, out);
}

// Round 10
// 137.475 us; speedup vs baseline: 1.4737x; 1.0040x over previous
//
#include <hip/hip_runtime.h>
#include <math.h>

#define NBINS 64
#define HIST_ELEMS (NBINS*NBINS)
#define PTS_PER_BLOCK 3456      // 256 blocks/n * 3456 = 884736 = P; grid 512 = 2/CU even
#define GXN 256                 // blocks per sample
#define TOTAL_HBLOCKS (GXN*2)
#define CHUNKS 27               // per wave: 3456 / (4 waves * 32)
#define LSTRIDE 68              // col-major lh stride (b128 2-way banks = free)
// weight = exp2(-(u*SQK - b*SQK)^2); SQK = sqrt(8192/63^2*log2(e))
#define SQK 1.7256062f
#define SMEM_FLOATS (2*PTS_PER_BLOCK + NBINS*LSTRIDE)   // 11264 floats = 44 KB

typedef float f4 __attribute__((ext_vector_type(4)));
typedef float f32x4 __attribute__((ext_vector_type(4)));
typedef _Float16 half8 __attribute__((ext_vector_type(8)));
typedef int int4v __attribute__((ext_vector_type(4)));

static __device__ __forceinline__ half8 pack8(const float* w) {
    int4v v;
    v[0] = __builtin_bit_cast(int, __builtin_amdgcn_cvt_pkrtz(w[0], w[1]));
    v[1] = __builtin_bit_cast(int, __builtin_amdgcn_cvt_pkrtz(w[2], w[3]));
    v[2] = __builtin_bit_cast(int, __builtin_amdgcn_cvt_pkrtz(w[4], w[5]));
    v[3] = __builtin_bit_cast(int, __builtin_amdgcn_cvt_pkrtz(w[6], w[7]));
    return __builtin_bit_cast(half8, v);
}

// ws layout (floats): pm[512]: [ (n*2+t)*64 + b ]=block min, [256 + ...]=block max
//                     @byte 2048: unsigned counter
//                     @byte 4096: float hist[2][4096]  (zeroed here each call)
__global__ __launch_bounds__(256) void minmax_kernel(const float* __restrict__ tar,
                                                     const float* __restrict__ src,
                                                     float* __restrict__ pm,
                                                     unsigned* __restrict__ ctr,
                                                     float* __restrict__ hist, int P) {
    const int b = blockIdx.x, n = blockIdx.y, t = blockIdx.z;
    const f4* x = (const f4*)((t == 0 ? tar : src) + (size_t)n * P);
    const int per = (P / 4) / 64;   // 3456 f4 per block
    float lmin = INFINITY, lmax = -INFINITY;
    for (int i = b * per + threadIdx.x; i < (b + 1) * per; i += 256) {
        f4 v = x[i];
        lmin = fminf(lmin, fminf(fminf(v[0], v[1]), fminf(v[2], v[3])));
        lmax = fmaxf(lmax, fmaxf(fmaxf(v[0], v[1]), fmaxf(v[2], v[3])));
    }
    for (int off = 32; off > 0; off >>= 1) {
        lmin = fminf(lmin, __shfl_down(lmin, off, 64));
        lmax = fmaxf(lmax, __shfl_down(lmax, off, 64));
    }
    __shared__ float smin[4], smax[4];
    const int lane = threadIdx.x & 63, wave = threadIdx.x >> 6;
    if (lane == 0) { smin[wave] = lmin; smax[wave] = lmax; }
    __syncthreads();
    if (threadIdx.x == 0) {
        pm[(n * 2 + t) * 64 + b] =
            fminf(fminf(smin[0], smin[1]), fminf(smin[2], smin[3]));
        pm[256 + (n * 2 + t) * 64 + b] =
            fmaxf(fmaxf(smax[0], smax[1]), fmaxf(smax[2], smax[3]));
    }
    // zero global hist (8192 floats over 256 blocks) + counter
    const int flat = b + 64 * n + 128 * t;   // 0..255
    if (threadIdx.x < 32) hist[flat * 32 + threadIdx.x] = 0.0f;
    if (flat == 0 && threadIdx.x == 0) *ctr = 0u;
}

// Fused: partial-minmax reduce + MFMA joint-hist (R9 core) + global atomic
// accumulate + last-block finalize.  2 dispatches total (launch overhead was
// ~15us/node x 5 nodes = the R9 bottleneck).
// A[m][k]: m=lane&15 (+16*mt), k=quad*8+j ; B[k][n]: n=lane&15, k=quad*8+j
// C/D: col=lane&15, row=quad*4+reg -> col-major lh, serial-wave non-atomic
// combine.  Output hist is TRANSPOSED (loss is transpose-invariant).
__global__ __launch_bounds__(256) void mfma_hist_fused(const float* __restrict__ tar,
                                                       const float* __restrict__ src,
                                                       const float* __restrict__ pm,
                                                       unsigned* __restrict__ ctr,
                                                       float* __restrict__ hist,
                                                       float* __restrict__ out, int P) {
    const int n = blockIdx.y;
    const int bx = blockIdx.x;
    const int tid = threadIdx.x;
    const int lane = tid & 63, wave = tid >> 6;
    const int mlane = lane & 15, quad = lane >> 4;

    __shared__ float smem[SMEM_FLOATS];
    __shared__ float mmred[4];
    __shared__ int lastflag;
    float* su_t = smem;
    float* su_s = smem + PTS_PER_BLOCK;
    float* lh = smem + 2 * PTS_PER_BLOCK;   // col-major: lh[col*LSTRIDE + row]

    // --- wave 0: reduce the 64 per-block minmax partials ---
    if (wave == 0) {
        float a = pm[(n * 2 + 0) * 64 + lane];
        float b = pm[256 + (n * 2 + 0) * 64 + lane];
        float c = pm[(n * 2 + 1) * 64 + lane];
        float d = pm[256 + (n * 2 + 1) * 64 + lane];
        for (int off = 32; off > 0; off >>= 1) {
            a = fminf(a, __shfl_down(a, off, 64));
            b = fmaxf(b, __shfl_down(b, off, 64));
            c = fminf(c, __shfl_down(c, off, 64));
            d = fmaxf(d, __shfl_down(d, off, 64));
        }
        if (lane == 0) { mmred[0] = a; mmred[1] = b; mmred[2] = c; mmred[3] = d; }
    }

    // --- stage raw inputs: 864 f4 per tensor, coalesced ---
    {
        const f4* tg = (const f4*)(tar + (size_t)n * P + (size_t)bx * PTS_PER_BLOCK);
        const f4* sg = (const f4*)(src + (size_t)n * P + (size_t)bx * PTS_PER_BLOCK);
        f4* st4 = (f4*)su_t;
        f4* ss4 = (f4*)su_s;
        #pragma unroll
        for (int k = 0; k < 3; ++k) {
            const int i = tid + k * 256;
            st4[i] = tg[i];
            ss4[i] = sg[i];
        }
        if (tid < 96) {
            const int i = 768 + tid;
            st4[i] = tg[i];
            ss4[i] = sg[i];
        }
    }
    __syncthreads();   // staging + mmred complete

    const float tmin = mmred[0], tmax = mmred[1];
    const float smin = mmred[2], smax = mmred[3];
    const float tk = 63.0f / (tmax - tmin + 1e-10f) * SQK;
    const float sk = 63.0f / (smax - smin + 1e-10f) * SQK;
    // scaling folded into the per-weight fma: d = x*tk - (tmin*tk + SQK*bin)
    float mt2[4], ms2[4];
    #pragma unroll
    for (int mt = 0; mt < 4; ++mt) {
        const float b = SQK * (float)(mlane + 16 * mt);
        mt2[mt] = tmin * tk + b;
        ms2[mt] = smin * sk + b;
    }

    f32x4 acc[4][4];
    #pragma unroll
    for (int a = 0; a < 4; ++a)
        #pragma unroll
        for (int b = 0; b < 4; ++b) acc[a][b] = (f32x4){0.f, 0.f, 0.f, 0.f};

    // --- compute: wave owns 864 points = 27 chunks of K=32, barrier-free ---
    const int kwbase = wave * (32 * CHUNKS) + quad * 8;
    #pragma unroll 3
    for (int c = 0; c < CHUNKS; ++c) {
        const int kbase = kwbase + c * 32;
        const f4* pt4 = (const f4*)&su_t[kbase];
        const f4* ps4 = (const f4*)&su_s[kbase];
        f4 ta = pt4[0], tb = pt4[1];
        f4 sa = ps4[0], sb = ps4[1];
        float xt[8] = {ta[0], ta[1], ta[2], ta[3], tb[0], tb[1], tb[2], tb[3]};
        float xs[8] = {sa[0], sa[1], sa[2], sa[3], sb[0], sb[1], sb[2], sb[3]};

        half8 af[4], bf[4];
        #pragma unroll
        for (int mt = 0; mt < 4; ++mt) {
            float w[8];
            #pragma unroll
            for (int j = 0; j < 8; ++j) {
                float d = fmaf(xt[j], tk, -mt2[mt]);
                w[j] = __builtin_amdgcn_exp2f(-(d * d));
            }
            af[mt] = pack8(w);
        }
        #pragma unroll
        for (int nt = 0; nt < 4; ++nt) {
            float w[8];
            #pragma unroll
            for (int j = 0; j < 8; ++j) {
                float d = fmaf(xs[j], sk, -ms2[nt]);
                w[j] = __builtin_amdgcn_exp2f(-(d * d));
            }
            bf[nt] = pack8(w);
        }
        #pragma unroll
        for (int mt = 0; mt < 4; ++mt)
            #pragma unroll
            for (int nt = 0; nt < 4; ++nt)
                acc[mt][nt] = __builtin_amdgcn_mfma_f32_16x16x32_f16(
                    af[mt], bf[nt], acc[mt][nt], 0, 0, 0);
    }

    // --- serial-wave non-atomic combine into col-major lh ---
    #pragma unroll
    for (int w = 0; w < 4; ++w) {
        if (wave == w) {
            #pragma unroll
            for (int nt = 0; nt < 4; ++nt)
                #pragma unroll
                for (int mt = 0; mt < 4; ++mt) {
                    f4* p = (f4*)&lh[(16 * nt + mlane) * LSTRIDE + 16 * mt + 4 * quad];
                    if (w == 0) {
                        *p = acc[mt][nt];
                    } else {
                        f4 v = *p;
                        v += acc[mt][nt];
                        *p = v;
                    }
                }
        }
        __syncthreads();
    }

    // --- flush tile into global hist (L2-resident 32 KB, HW fp atomics) ---
    float* gh = hist + (size_t)n * HIST_ELEMS;
    for (int i = tid; i < HIST_ELEMS; i += 256) {
        const int c = i >> 6, r = i & 63;
        unsafeAtomicAdd(&gh[i], lh[c * LSTRIDE + r]);
    }

    // --- last-block finalize ---
    __threadfence();
    if (tid == 0) {
        unsigned old = atomicAdd(ctr, 1u);
        lastflag = (old == TOTAL_HBLOCKS - 1) ? 1 : 0;
    }
    __syncthreads();
    if (!lastflag) return;
    __threadfence();

    // load final hist (both samples) into smem via agent-scope loads
    for (int i = tid; i < 2 * HIST_ELEMS; i += 256)
        smem[i] = __hip_atomic_load(&hist[i], __ATOMIC_RELAXED, __HIP_MEMORY_SCOPE_AGENT);
    __syncthreads();

    float* buf    = smem + 2 * HIST_ELEMS;        // 4
    float* rowsum = smem + 2 * HIST_ELEMS + 4;    // 64
    float* colsum = smem + 2 * HIST_ELEMS + 68;   // 64
    float* colp   = smem + 2 * HIST_ELEMS + 132;  // 256
    float accl = 0.0f;
    for (int nn = 0; nn < 2; ++nn) {
        const float* h = smem + nn * HIST_ELEMS;
        {
            int r = tid >> 2, q = tid & 3;
            const float* hp = h + r * NBINS + q * 16;
            float sv = 0.0f;
            #pragma unroll
            for (int k = 0; k < 16; ++k) sv += hp[k];
            sv += __shfl_down(sv, 1, 64);
            sv += __shfl_down(sv, 2, 64);
            if (q == 0) rowsum[r] = sv;
        }
        {
            int c = tid & 63, g = tid >> 6;
            const float* hp = h + (g * 16) * NBINS + c;
            float sv = 0.0f;
            #pragma unroll
            for (int k = 0; k < 16; ++k) sv += hp[k * NBINS];
            colp[g * NBINS + c] = sv;
        }
        __syncthreads();
        if (tid < NBINS)
            colsum[tid] = colp[0 * NBINS + tid] + colp[1 * NBINS + tid] +
                          colp[2 * NBINS + tid] + colp[3 * NBINS + tid];
        __syncthreads();

        float tv = (tid < NBINS) ? rowsum[tid] : 0.0f;
        // block reduce
        for (int off = 32; off > 0; off >>= 1) tv += __shfl_down(tv, off, 64);
        __syncthreads();
        if (lane == 0) buf[wave] = tv;
        __syncthreads();
        const float total = buf[0] + buf[1] + buf[2] + buf[3];
        const float inv = 1.0f / total;

        float ej = 0.0f;
        for (int i = tid; i < HIST_ELEMS; i += 256) {
            float p = h[i] * inv;
            ej += p * __logf(p + 1e-10f);
        }
        for (int off = 32; off > 0; off >>= 1) ej += __shfl_down(ej, off, 64);
        __syncthreads();
        if (lane == 0) buf[wave] = ej;
        __syncthreads();
        const float entj = -(buf[0] + buf[1] + buf[2] + buf[3]);

        float em = 0.0f;
        if (tid < NBINS) {
            float p = rowsum[tid] * inv;
            em = p * __logf(p + 1e-10f);
        } else if (tid < 2 * NBINS) {
            float p = colsum[tid - NBINS] * inv;
            em = p * __logf(p + 1e-10f);
        }
        for (int off = 32; off > 0; off >>= 1) em += __shfl_down(em, off, 64);
        __syncthreads();
        if (lane == 0) buf[wave] = em;
        __syncthreads();
        const float ents = -(buf[0] + buf[1] + buf[2] + buf[3]);

        accl += ents / entj;
        __syncthreads();
    }
    if (tid == 0) out[0] = -0.5f * accl;
}

extern "C" void kernel_launch(void* const* d_in, const int* in_sizes, int n_in,
                              void* d_out, int out_size, void* d_ws, size_t ws_size,
                              hipStream_t stream) {
    const float* tar = (const float*)d_in[0];
    const float* src = (const float*)d_in[1];
    const int N = 2;
    const int P = in_sizes[0] / N;  // 884736

    float* pm = (float*)d_ws;
    unsigned* ctr = (unsigned*)((char*)d_ws + 2048);
    float* hist = (float*)((char*)d_ws + 4096);
    float* out = (float*)d_out;

    minmax_kernel<<<dim3(64, N, 2), 256, 0, stream>>>(tar, src, pm, ctr, hist, P);
    mfma_hist_fused<<<dim3(GXN, N), 256, 0, stream>>>(tar, src, pm, ctr, hist, out, P);
}